// Round 2
// baseline (234.518 us; speedup 1.0000x reference)
//
#include <hip/hip_runtime.h>

// Sobel |gx|+|gy|+eps, SAME zero padding. Input (32,1,1024,1024) fp32.
//
// R5: async global->LDS DMA pipeline with counted vmcnt (T3/T4 pattern).
// R4 post-mortem: compiler sank the register-pipeline loads to first use
// (VGPR=32 < 36 floats of buffer => pipeline collapsed, dur unchanged 85us,
// ~0.5 loads/wave in flight). Fix: global_load_lds DMA consumes NO VGPRs,
// so the compiler cannot collapse the prefetch depth; explicit counted
// s_waitcnt vmcnt(N) (never 0 in-loop) keeps P=4 rows (4KB/wave, 128KB/CU)
// in flight -- >>9KB/CU needed to saturate ~6.3TB/s at ~900cy latency.
//
// Structure per block (256 thr, one 16-row strip, full 1024 width):
//  - circular LDS row buffer: NB=5 rows x 4KB = 20KB => 8 blocks/CU (160KB)
//  - each wave DMAs its 1KB quarter of a row (1 global_load_lds_dwordx4)
//  - per iter: waitcnt vmcnt(N) [asm+sched_barrier, rule #18] -> s_barrier
//    -> issue DMA row y+3 -> ds_read new row y+1 (3x aligned b128,
//    conflict-free stride-16) -> compute from reg T/M/B window -> nt-store
//  - halo columns via cndmask (edge lanes), OOB rows zeroed at consume,
//    DMA row index clamped to [0,H-1] so counting stays uniform
// vmcnt bookkeeping per wave (loads L0..L17, stores S0..S15 both count):
//   prologue vmcnt(2); iter0:1, iter1:2, iters2..14:3, iter15:2.
// XCD swizzle + nontemporal stores kept from R3/R4.

#define W 1024
#define H 1024
#define R 16          // rows per block strip (64 strips/image)
#define NB 5          // LDS row slots (circular)
#define EPS 1e-5f

typedef float v4f __attribute__((ext_vector_type(4)));

#define WAITVM(n)                                          \
    do {                                                   \
        asm volatile("s_waitcnt vmcnt(" #n ")" ::: "memory"); \
        __builtin_amdgcn_sched_barrier(0);                 \
    } while (0)

#define GLOAD_LDS16(g, l)                                                     \
    __builtin_amdgcn_global_load_lds(                                         \
        (const __attribute__((address_space(1))) void*)(g),                   \
        (__attribute__((address_space(3))) void*)(l), 16, 0, 0)

__global__ __launch_bounds__(256, 8) void sobel_kernel(const float* __restrict__ in,
                                                       float* __restrict__ out) {
    __shared__ float lds[NB * W];   // 20 KB

    // XCD swizzle: same-XCD blocks handle 8 adjacent strips (halo L2 reuse).
    const int b = blockIdx.x;                  // 0..2047
    const int t = ((b & 255) << 3) | (b >> 8); // bijective swizzle
    const int img = t >> 6;                    // 64 strips per image
    const int ty = (t & 63) * R;               // first output row of strip
    const int tid = threadIdx.x;
    const int x0 = tid << 2;
    const int wave = tid >> 6;

    const bool t0 = (tid == 0);
    const bool tN = (tid == 255);
    const int cl = t0 ? 0 : (x0 - 4);   // aligned 16B block holding x0-1
    const int cr = tN ? x0 : (x0 + 4);  // aligned 16B block holding x0+4

    const float* base  = in  + (size_t)img * (W * H);
    float*       obase = out + (size_t)img * (W * H);

    // Issue DMA of row y (clamped) into slot s. Wave-uniform LDS dest
    // (slot + wave*1KB); HW adds lane*16B -> linear row layout.
    auto dma = [&](int y, int s) {
        const int yc = (y < 0) ? 0 : ((y > H - 1) ? (H - 1) : y);
        const float* g = base + (size_t)yc * W + x0;
        GLOAD_LDS16(g, lds + s * W + (wave << 8));
    };

    // Read row from slot s into d[0..5] = row[x0-1 .. x0+4]; edge lanes and
    // fully-OOB rows (uniform `zero`) repaired with selects.
    auto ldrow = [&](int s, float* d, bool zero) {
        const float* p = lds + s * W;
        v4f A = *(const v4f*)(p + cl);
        v4f M = *(const v4f*)(p + x0);
        v4f C = *(const v4f*)(p + cr);
        float l = t0 ? 0.f : A.w;
        float r = tN ? 0.f : C.x;
        d[0] = zero ? 0.f : l;
        d[1] = zero ? 0.f : M.x;
        d[2] = zero ? 0.f : M.y;
        d[3] = zero ? 0.f : M.z;
        d[4] = zero ? 0.f : M.w;
        d[5] = zero ? 0.f : r;
    };

    // Prologue: DMA rows ty-1 .. ty+2 into slots 0..3 (4 loads in flight).
    dma(ty - 1, 0);
    dma(ty,     1);
    dma(ty + 1, 2);
    dma(ty + 2, 3);

    WAITVM(2);                       // rows ty-1, ty landed
    __builtin_amdgcn_s_barrier();

    float Tw[6], Mw[6], Bw[6];
    ldrow(0, Tw, ty == 0);           // row ty-1 (zero for top strip)
    ldrow(1, Mw, false);             // row ty

#pragma unroll
    for (int i = 0; i < R; ++i) {
        // Wait for row ty+i+1 (load L_{i+2}); stores/loads after it stay in flight.
        if (i == 0)            WAITVM(1);
        else if (i == 1)       WAITVM(2);
        else if (i == R - 1)   WAITVM(2);
        else                   WAITVM(3);
        __builtin_amdgcn_s_barrier();

        // Prefetch row ty+i+3 into slot (i+4)%NB (distinct from read slots
        // (i..i+2)%NB; old content's last reader was iter i-1 -> safe).
        if (i <= R - 3) dma(ty + i + 3, (i + 4) % NB);

        // New bottom row y+1 from LDS slot (i+2)%NB.
        ldrow((i + 2) % NB, Bw, ty + i + 1 >= H);

        v4f o;
#pragma unroll
        for (int j = 0; j < 4; ++j) {
            // Sobel X: [[-1,0,1],[-2,0,2],[-1,0,1]]
            float gx = (Tw[j + 2] - Tw[j]) + 2.0f * (Mw[j + 2] - Mw[j]) + (Bw[j + 2] - Bw[j]);
            // Sobel Y: [[-1,-2,-1],[0,0,0],[1,2,1]]
            float gy = (Bw[j] + 2.0f * Bw[j + 1] + Bw[j + 2]) - (Tw[j] + 2.0f * Tw[j + 1] + Tw[j + 2]);
            o[j] = fabsf(gx) + fabsf(gy) + EPS;
        }
        __builtin_nontemporal_store(o, (v4f*)(obase + (size_t)(ty + i) * W + x0));

#pragma unroll
        for (int j = 0; j < 6; ++j) { Tw[j] = Mw[j]; Mw[j] = Bw[j]; }
    }
}

extern "C" void kernel_launch(void* const* d_in, const int* in_sizes, int n_in,
                              void* d_out, int out_size, void* d_ws, size_t ws_size,
                              hipStream_t stream) {
    const float* x = (const float*)d_in[0];
    float* outp = (float*)d_out;
    const int N = 32;
    dim3 grid(N * (H / R));   // 32 * 64 = 2048 blocks
    dim3 block(256);
    sobel_kernel<<<grid, block, 0, stream>>>(x, outp);
}